// Round 3
// baseline (596.245 us; speedup 1.0000x reference)
//
#include <hip/hip_runtime.h>
#include <cstddef>
#include <cstdint>

#define DIM   256
#define KCODE 8192
#define NTOK  16384
#define NCB   64          // code blocks (8192/128)
#define MARGIN 0.5f

typedef __attribute__((ext_vector_type(8))) short short8;
typedef __attribute__((ext_vector_type(8))) unsigned short ushort8;
typedef __attribute__((ext_vector_type(4))) float floatx4;

// RNE float->bf16
__device__ __forceinline__ unsigned short f2bf(float f) {
  uint32_t u = __builtin_bit_cast(uint32_t, f);
  return (unsigned short)((u + 0x7fffu + ((u >> 16) & 1u)) >> 16);
}

// async 16B global->LDS (per-lane global addr, wave-uniform LDS base + lane*16)
__device__ __forceinline__ void async16(const unsigned short* g, unsigned short* l) {
  __builtin_amdgcn_global_load_lds(
      (const __attribute__((address_space(1))) void*)g,
      (__attribute__((address_space(3))) void*)l, 16, 0, 0);
}

// ---- kernel 1: fused bf16 convert + row sumsq for x and w ----
// grid 3072 x 256: block covers 8 rows of 256 (4 waves x 2 rows)
__global__ __launch_bounds__(256) void prep_kernel(const float* __restrict__ x,
    const float* __restrict__ w, unsigned short* __restrict__ x0,
    unsigned short* __restrict__ w0, float* __restrict__ sumx,
    float* __restrict__ wn, int* __restrict__ ucount) {
  if (blockIdx.x == 0 && threadIdx.x == 0) *ucount = 0;
  const int lane = threadIdx.x & 63, wv = threadIdx.x >> 6;
  const int l32 = lane & 31;
  const int row = blockIdx.x * 8 + wv * 2 + (lane >> 5);
  const float* src;
  unsigned short* dst;
  if (row < NTOK) { src = x + (size_t)row * DIM; dst = x0 + (size_t)row * DIM; }
  else { src = w + (size_t)(row - NTOK) * DIM; dst = w0 + (size_t)(row - NTOK) * DIM; }
  const float4 f0 = ((const float4*)src)[l32 * 2];
  const float4 f1 = ((const float4*)src)[l32 * 2 + 1];
  ushort8 o;
  o[0] = f2bf(f0.x); o[1] = f2bf(f0.y); o[2] = f2bf(f0.z); o[3] = f2bf(f0.w);
  o[4] = f2bf(f1.x); o[5] = f2bf(f1.y); o[6] = f2bf(f1.z); o[7] = f2bf(f1.w);
  *(ushort8*)(dst + l32 * 8) = o;
  float s = f0.x * f0.x + f0.y * f0.y + f0.z * f0.z + f0.w * f0.w +
            f1.x * f1.x + f1.y * f1.y + f1.z * f1.z + f1.w * f1.w;
#pragma unroll
  for (int off = 1; off < 32; off <<= 1) s += __shfl_xor(s, off);
  if (l32 == 0) {
    if (row < NTOK) sumx[row] = s; else wn[row - NTOK] = s;
  }
}

// ---- kernel 2: bf16 MFMA GEMM, global_load_lds staging, top-2 epilogue ----
__global__ __launch_bounds__(256) void phase1_kernel(
    const unsigned short* __restrict__ x0, const unsigned short* __restrict__ w0,
    const float* __restrict__ wnorm,
    float* __restrict__ pv1, int* __restrict__ pc1, float* __restrict__ pv2) {
  __shared__ char smem[49152];
  unsigned short* As = (unsigned short*)smem;            // [128][32] bf16, 8 KB
  unsigned short* Bs = (unsigned short*)(smem + 8192);   // [128][32] bf16, 8 KB
  float* rv1 = (float*)smem;                             // epilogue reuse: [128][32]
  int*   rc1 = (int*)(smem + 16384);
  float* rv2 = (float*)(smem + 32768);

  const int tid = threadIdx.x;
  const int tb = blockIdx.x & 127;   // tb fastest: each XCD sees 1/8 of x0 + all w0 (~5MB ~ L2)
  const int cb = blockIdx.x >> 7;
  const int lane = tid & 63;
  const int wv = tid >> 6;
  const int wm = wv & 1;        // token half
  const int wnn = wv >> 1;      // code half
  const int l15 = lane & 15, quad = lane >> 4;

  floatx4 acc[4][4];
#pragma unroll
  for (int mt = 0; mt < 4; ++mt)
#pragma unroll
    for (int nt = 0; nt < 4; ++nt) acc[mt][nt] = (floatx4){0.f, 0.f, 0.f, 0.f};

  // staging geometry: wave wv covers rows [wv*32, wv*32+32), 2 instr each for A and B;
  // lane i -> row += i/4, 16B col chunk (i%4). LDS lands row-major [row][32] unpadded.
  const int srow = lane >> 2;
  const int scol = (lane & 3) * 8;
  const unsigned short* xbase = x0 + (size_t)(tb * 128) * DIM;
  const unsigned short* wbase = w0 + (size_t)(cb * 128) * DIM;

  for (int kc = 0; kc < 8; ++kc) {
    const int k0 = kc * 32;
    __syncthreads();
#pragma unroll
    for (int j = 0; j < 2; ++j)
      async16(xbase + (size_t)(wv * 32 + j * 16 + srow) * DIM + k0 + scol,
              As + (wv * 32 + j * 16) * 32);
#pragma unroll
    for (int j = 0; j < 2; ++j)
      async16(wbase + (size_t)(wv * 32 + j * 16 + srow) * DIM + k0 + scol,
              Bs + (wv * 32 + j * 16) * 32);
    __syncthreads();
    short8 af[4], bf[4];
#pragma unroll
    for (int mt = 0; mt < 4; ++mt)
      af[mt] = *(const short8*)(As + (wm * 64 + mt * 16 + l15) * 32 + quad * 8);
#pragma unroll
    for (int nt = 0; nt < 4; ++nt)
      bf[nt] = *(const short8*)(Bs + (wnn * 64 + nt * 16 + l15) * 32 + quad * 8);
#pragma unroll
    for (int mt = 0; mt < 4; ++mt)
#pragma unroll
      for (int nt = 0; nt < 4; ++nt)
        acc[mt][nt] = __builtin_amdgcn_mfma_f32_16x16x32_bf16(af[mt], bf[nt], acc[mt][nt], 0, 0, 0);
  }

  // ---- epilogue: approx dist = wn - 2*dot ; exact top-2 within block ----
  __syncthreads();
  float wnv[4];
#pragma unroll
  for (int nt = 0; nt < 4; ++nt)
    wnv[nt] = wnorm[cb * 128 + wnn * 64 + nt * 16 + l15];

#pragma unroll
  for (int mt = 0; mt < 4; ++mt) {
#pragma unroll
    for (int reg = 0; reg < 4; ++reg) {
      float v[4];
#pragma unroll
      for (int nt = 0; nt < 4; ++nt) v[nt] = wnv[nt] - 2.0f * acc[mt][nt][reg];
      float bv1 = v[0], bv2 = -3.4e38f;
      int bnt = 0;
#pragma unroll
      for (int j = 1; j < 4; ++j) {
        if (v[j] > bv1) { bv2 = bv1; bv1 = v[j]; bnt = j; }
        else bv2 = fmaxf(bv2, v[j]);
      }
      const int tok = wm * 64 + mt * 16 + quad * 4 + reg;  // C/D: row=quad*4+reg
      const int cg = wnn * 16 + l15;                       // C/D: col=lane&15
      rv1[tok * 32 + cg] = bv1;
      rc1[tok * 32 + cg] = cb * 128 + wnn * 64 + bnt * 16 + l15;
      rv2[tok * 32 + cg] = bv2;
    }
  }
  __syncthreads();
  if (tid < 128) {
    float V1 = rv1[tid * 32], V2 = rv2[tid * 32];
    int C1 = rc1[tid * 32];
#pragma unroll 4
    for (int j = 1; j < 32; ++j) {
      const float v1 = rv1[tid * 32 + j], v2 = rv2[tid * 32 + j];
      const int c1 = rc1[tid * 32 + j];
      if (v1 > V1) { V2 = fmaxf(V1, v2); V1 = v1; C1 = c1; }
      else V2 = fmaxf(V2, v1);   // tie -> gap 0 -> uncertain -> exact rescore
    }
    const size_t o = (size_t)cb * NTOK + tb * 128 + tid;
    pv1[o] = V1; pc1[o] = C1; pv2[o] = V2;
  }
}

// ---- kernel 3: merge 64 col-block partials; final idx + uncertain list ----
__global__ __launch_bounds__(256) void reduce_kernel(
    const float* __restrict__ pv1, const int* __restrict__ pc1,
    const float* __restrict__ pv2, int* __restrict__ final_idx,
    int* __restrict__ ucount, int* __restrict__ ulist) {
  const int n = blockIdx.x * 256 + threadIdx.x;
  float V1 = -3.4e38f, V2 = -3.4e38f;
  int C1 = 0;
  for (int cb = 0; cb < NCB; ++cb) {
    const size_t o = (size_t)cb * NTOK + n;
    const float v1 = pv1[o], v2 = pv2[o];
    const int c1 = pc1[o];
    if (v1 > V1) { V2 = fmaxf(V1, v2); V1 = v1; C1 = c1; }
    else V2 = fmaxf(V2, v1);
  }
  final_idx[n] = C1;
  if (V1 - V2 < MARGIN) {
    const int p = atomicAdd(ucount, 1);
    ulist[p] = n;
  }
}

// ---- kernel 4: exact fp32 rescore, coalesced geometry ----
// block = (slice sl of 1024 codes, g); token slots s = g, g+512, ...
// thread = (code group g16 = tid>>4, dim group d16 = tid&15)
__global__ __launch_bounds__(256) void rescore_kernel(
    const float* __restrict__ x, const float* __restrict__ w,
    const float* __restrict__ wnorm, const float* __restrict__ sumx,
    const int* __restrict__ ucount, const int* __restrict__ ulist,
    float* __restrict__ p2v, int* __restrict__ p2c) {
  const int uc = *ucount;
  const int sl = blockIdx.x & 7, g = blockIdx.x >> 3;
  __shared__ float xs[DIM];
  __shared__ float bestv_s[4];
  __shared__ int bestc_s[4];
  const int tid = threadIdx.x;
  const int g16 = tid >> 4, d16 = tid & 15;

  for (int s = g; s < uc; s += 512) {
    const int tok = ulist[s];
    __syncthreads();
    if (tid < 64) ((float4*)xs)[tid] = ((const float4*)(x + (size_t)tok * DIM))[tid];
    __syncthreads();
    const float sx = sumx[tok];
    float4 xq[4];
#pragma unroll
    for (int q = 0; q < 4; ++q) xq[q] = ((const float4*)xs)[d16 * 4 + q];

    float bv = -3.4e38f;
    int bc = 0;
    for (int it = 0; it < 64; ++it) {
      const int c = sl * 1024 + it * 16 + g16;
      const float4* wr = (const float4*)(w + (size_t)c * DIM) + d16 * 4;
      float p = 0.f;
#pragma unroll
      for (int q = 0; q < 4; ++q) {
        const float4 wv4 = wr[q];
        p = fmaf(xq[q].x, wv4.x, p);
        p = fmaf(xq[q].y, wv4.y, p);
        p = fmaf(xq[q].z, wv4.z, p);
        p = fmaf(xq[q].w, wv4.w, p);
      }
      // butterfly sum across the 16 dim-lanes (all lanes end with full dot)
      p += __shfl_xor(p, 1); p += __shfl_xor(p, 2);
      p += __shfl_xor(p, 4); p += __shfl_xor(p, 8);
      const float dist = (sx + wnorm[c]) - 2.0f * p;
      if (dist > bv) { bv = dist; bc = c; }   // ascending c per thread -> lowest tie
    }
    // merge the 4 code-groups within each wave (lowest-code ties)
#pragma unroll
    for (int off = 16; off < 64; off <<= 1) {
      const float ov = __shfl_xor(bv, off);
      const int oc = __shfl_xor(bc, off);
      if (ov > bv || (ov == bv && oc < bc)) { bv = ov; bc = oc; }
    }
    if ((tid & 63) == 0) { bestv_s[tid >> 6] = bv; bestc_s[tid >> 6] = bc; }
    __syncthreads();
    if (tid == 0) {
      float V = bestv_s[0];
      int C = bestc_s[0];
#pragma unroll
      for (int k = 1; k < 4; ++k) {
        const float v = bestv_s[k];
        const int c2 = bestc_s[k];
        if (v > V || (v == V && c2 < C)) { V = v; C = c2; }
      }
      p2v[(sl << 14) + s] = V;
      p2c[(sl << 14) + s] = C;
    }
  }
}

// ---- kernel 5: merge 8 slices per uncertain token ----
__global__ __launch_bounds__(256) void p2merge_kernel(const int* __restrict__ ucount,
    const int* __restrict__ ulist, const float* __restrict__ p2v,
    const int* __restrict__ p2c, int* __restrict__ final_idx) {
  const int s = blockIdx.x * 256 + threadIdx.x;
  if (s >= *ucount) return;
  float V = -3.4e38f;
  int C = 0;
#pragma unroll
  for (int sl = 0; sl < 8; ++sl) {
    const float v = p2v[(sl << 14) + s];
    const int c = p2c[(sl << 14) + s];
    if (v > V || (v == V && c < C)) { V = v; C = c; }
  }
  final_idx[ulist[s]] = C;
}

// ---- kernel 6: gather output rows ----
__global__ __launch_bounds__(256) void gather_kernel(const float* __restrict__ w,
    const int* __restrict__ final_idx, float* __restrict__ out) {
  const int lane = threadIdx.x & 63;
  const int n = blockIdx.x * 4 + (threadIdx.x >> 6);
  const int bi = final_idx[n];
  ((float4*)(out + (size_t)n * DIM))[lane] = ((const float4*)(w + (size_t)bi * DIM))[lane];
}

extern "C" void kernel_launch(void* const* d_in, const int* in_sizes, int n_in,
                              void* d_out, int out_size, void* d_ws, size_t ws_size,
                              hipStream_t stream) {
  const float* x = (const float*)d_in[0];
  const float* w = (const float*)d_in[1];
  float* out = (float*)d_out;

  char* ws = (char*)d_ws;   // ~26.4 MB used
  unsigned short* x0 = (unsigned short*)(ws);                 // 8388608 B
  unsigned short* w0 = (unsigned short*)(ws + 8388608);       // 4194304 B
  float* wn   = (float*)(ws + 12582912);                      // 32768 B
  float* sumx = (float*)(ws + 12615680);                      // 65536 B
  float* pv1  = (float*)(ws + 12681216);                      // 4194304 B
  int*   pc1  = (int*)  (ws + 16875520);                      // 4194304 B
  float* pv2  = (float*)(ws + 21069824);                      // 4194304 B
  int* final_idx = (int*)(ws + 25264128);                     // 65536 B
  int* ucount = (int*)(ws + 25329664);                        // 64 B
  int* ulist  = (int*)(ws + 25329728);                        // 65536 B
  float* p2v  = (float*)(ws + 25395264);                      // 524288 B
  int*   p2c  = (int*)  (ws + 25919552);                      // 524288 B

  prep_kernel<<<3072, 256, 0, stream>>>(x, w, x0, w0, sumx, wn, ucount);
  phase1_kernel<<<128 * NCB, 256, 0, stream>>>(x0, w0, wn, pv1, pc1, pv2);
  reduce_kernel<<<NTOK / 256, 256, 0, stream>>>(pv1, pc1, pv2, final_idx, ucount, ulist);
  rescore_kernel<<<512 * 8, 256, 0, stream>>>(x, w, wn, sumx, ucount, ulist, p2v, p2c);
  p2merge_kernel<<<NTOK / 256, 256, 0, stream>>>(ucount, ulist, p2v, p2c, final_idx);
  gather_kernel<<<NTOK / 4, 256, 0, stream>>>(w, final_idx, out);
}

// Round 4
// 390.635 us; speedup vs baseline: 1.5263x; 1.5263x over previous
//
#include <hip/hip_runtime.h>
#include <cstddef>
#include <cstdint>

#define DIM   256
#define KCODE 8192
#define NTOK  16384
#define NCBG  4          // code groups of 2048 in phase1
#define HMARGIN 0.25f    // phase1 works in half-units (0.5*wn - dot); 0.25 = 0.5 full

typedef __attribute__((ext_vector_type(8))) short short8;
typedef __attribute__((ext_vector_type(8))) unsigned short ushort8;
typedef __attribute__((ext_vector_type(4))) float floatx4;

// RNE float->bf16
__device__ __forceinline__ unsigned short f2bf(float f) {
  uint32_t u = __builtin_bit_cast(uint32_t, f);
  return (unsigned short)((u + 0x7fffu + ((u >> 16) & 1u)) >> 16);
}

// ---- kernel 1: bf16 convert (x NEGATED) + row sumsq; 8 rows/block ----
__global__ __launch_bounds__(256) void prep_kernel(const float* __restrict__ x,
    const float* __restrict__ w, unsigned short* __restrict__ x0n,
    unsigned short* __restrict__ w0, float* __restrict__ sumx,
    float* __restrict__ wn2, float* __restrict__ wnf, int* __restrict__ ucount) {
  if (blockIdx.x == 0 && threadIdx.x == 0) *ucount = 0;
  const int lane = threadIdx.x & 63, wv = threadIdx.x >> 6;
  const int l32 = lane & 31;
  const int row = blockIdx.x * 8 + wv * 2 + (lane >> 5);
  const bool is_x = row < NTOK;
  const float* src = is_x ? (x + (size_t)row * DIM) : (w + (size_t)(row - NTOK) * DIM);
  const float4 f0 = ((const float4*)src)[l32 * 2];
  const float4 f1 = ((const float4*)src)[l32 * 2 + 1];
  ushort8 o;
  if (is_x) {  // store NEGATED x in bf16: MFMA then accumulates wn/2 - dot directly
    o[0] = f2bf(-f0.x); o[1] = f2bf(-f0.y); o[2] = f2bf(-f0.z); o[3] = f2bf(-f0.w);
    o[4] = f2bf(-f1.x); o[5] = f2bf(-f1.y); o[6] = f2bf(-f1.z); o[7] = f2bf(-f1.w);
    *(ushort8*)(x0n + (size_t)row * DIM + l32 * 8) = o;
  } else {
    o[0] = f2bf(f0.x); o[1] = f2bf(f0.y); o[2] = f2bf(f0.z); o[3] = f2bf(f0.w);
    o[4] = f2bf(f1.x); o[5] = f2bf(f1.y); o[6] = f2bf(f1.z); o[7] = f2bf(f1.w);
    *(ushort8*)(w0 + (size_t)(row - NTOK) * DIM + l32 * 8) = o;
  }
  float s = f0.x * f0.x + f0.y * f0.y + f0.z * f0.z + f0.w * f0.w +
            f1.x * f1.x + f1.y * f1.y + f1.z * f1.z + f1.w * f1.w;
#pragma unroll
  for (int off = 1; off < 32; off <<= 1) s += __shfl_xor(s, off);
  if (l32 == 0) {
    if (is_x) sumx[row] = s;
    else { wn2[row - NTOK] = 0.5f * s; wnf[row - NTOK] = s; }
  }
}

// ---- kernel 2: phase1 — A in VGPRs, B streamed from global, no main-loop LDS ----
// block = 128 tokens x 2048 codes; 4 waves: wm=token half(64), wnn=code half(32/sub)
__global__ __launch_bounds__(256, 2) void phase1_kernel(
    const unsigned short* __restrict__ x0n, const unsigned short* __restrict__ w0,
    const float* __restrict__ wn2,
    float* __restrict__ pv1, int* __restrict__ pc1, float* __restrict__ pv2) {
  __shared__ float red[12288];  // 48 KB: rv1[4096] rv2[4096] rc1[4096]
  const int tid = threadIdx.x;
  const int tb = blockIdx.x >> 2;    // 0..127
  const int cbg = blockIdx.x & 3;    // blockIdx%8 fixes XCD -> fixes cbg: 1MB w0 slice/XCD L2
  const int lane = tid & 63, wv = tid >> 6;
  const int wm = wv & 1, wnn = wv >> 1;
  const int l15 = lane & 15, quad = lane >> 4;

  // preload A fragments: 4 mt x 8 kc (negated-x bf16), 128 VGPRs
  short8 af[4][8];
#pragma unroll
  for (int mt = 0; mt < 4; ++mt) {
    const unsigned short* xr =
        x0n + (size_t)(tb * 128 + wm * 64 + mt * 16 + l15) * DIM + quad * 8;
#pragma unroll
    for (int kc = 0; kc < 8; ++kc) af[mt][kc] = *(const short8*)(xr + kc * 32);
  }

  float bv1[16], bv2[16];
  int bc1[16];
#pragma unroll
  for (int i = 0; i < 16; ++i) { bv1[i] = -3.4e38f; bv2[i] = -3.4e38f; bc1[i] = 0; }

#pragma unroll 1
  for (int sub = 0; sub < 32; ++sub) {
    const int cbase = cbg * 2048 + sub * 64 + wnn * 32;
    float wn2v[2];
#pragma unroll
    for (int nt = 0; nt < 2; ++nt) wn2v[nt] = wn2[cbase + nt * 16 + l15];
    floatx4 acc[4][2];
#pragma unroll
    for (int mt = 0; mt < 4; ++mt)
#pragma unroll
      for (int nt = 0; nt < 2; ++nt)
        acc[mt][nt] = (floatx4){wn2v[nt], wn2v[nt], wn2v[nt], wn2v[nt]};
#pragma unroll
    for (int kc = 0; kc < 8; ++kc) {
      short8 bf[2];
#pragma unroll
      for (int nt = 0; nt < 2; ++nt)
        bf[nt] = *(const short8*)(w0 + (size_t)(cbase + nt * 16 + l15) * DIM + kc * 32 + quad * 8);
#pragma unroll
      for (int mt = 0; mt < 4; ++mt)
#pragma unroll
        for (int nt = 0; nt < 2; ++nt)
          acc[mt][nt] = __builtin_amdgcn_mfma_f32_16x16x32_bf16(af[mt][kc], bf[nt], acc[mt][nt], 0, 0, 0);
    }
    // acc = wn/2 - dot (half-dist). Merge 2 candidates/cell into running top-2.
    const int code0 = cbase + l15, code1 = cbase + 16 + l15;
#pragma unroll
    for (int mt = 0; mt < 4; ++mt) {
#pragma unroll
      for (int reg = 0; reg < 4; ++reg) {
        const int cell = mt * 4 + reg;
        const float c0 = acc[mt][0][reg], c1 = acc[mt][1][reg];
        const bool s1 = c1 > c0;
        const float hi = s1 ? c1 : c0, lo = s1 ? c0 : c1;
        const int ch = s1 ? code1 : code0;
        if (hi > bv1[cell]) {
          bv2[cell] = fmaxf(bv1[cell], lo);
          bv1[cell] = hi;
          bc1[cell] = ch;
        } else {
          bv2[cell] = fmaxf(bv2[cell], hi);
        }
      }
    }
  }

  // single per-block epilogue: cross-column reduce via LDS
  float* rv1 = red;
  float* rv2 = red + 4096;
  int* rc1 = (int*)(red + 8192);
  const int cg = wnn * 16 + l15;
#pragma unroll
  for (int mt = 0; mt < 4; ++mt)
#pragma unroll
    for (int reg = 0; reg < 4; ++reg) {
      const int tok = wm * 64 + mt * 16 + quad * 4 + reg;  // C/D: row=quad*4+reg, col=l15
      rv1[tok * 32 + cg] = bv1[mt * 4 + reg];
      rv2[tok * 32 + cg] = bv2[mt * 4 + reg];
      rc1[tok * 32 + cg] = bc1[mt * 4 + reg];
    }
  __syncthreads();
  if (tid < 128) {
    float V1 = rv1[tid * 32], V2 = rv2[tid * 32];
    int C1 = rc1[tid * 32];
#pragma unroll 4
    for (int j = 1; j < 32; ++j) {
      const float v1 = rv1[tid * 32 + j], v2 = rv2[tid * 32 + j];
      const int c1 = rc1[tid * 32 + j];
      if (v1 > V1) { V2 = fmaxf(V1, v2); V1 = v1; C1 = c1; }
      else V2 = fmaxf(V2, v1);   // exact tie -> gap 0 -> uncertain -> exact rescore
    }
    const size_t o = (size_t)cbg * NTOK + tb * 128 + tid;
    pv1[o] = V1; pc1[o] = C1; pv2[o] = V2;
  }
}

// ---- kernel 3: merge 4 code-group partials; final idx + uncertain list ----
__global__ __launch_bounds__(256) void reduce_kernel(
    const float* __restrict__ pv1, const int* __restrict__ pc1,
    const float* __restrict__ pv2, int* __restrict__ final_idx,
    int* __restrict__ ucount, int* __restrict__ ulist) {
  const int n = blockIdx.x * 256 + threadIdx.x;
  float V1 = -3.4e38f, V2 = -3.4e38f;
  int C1 = 0;
#pragma unroll
  for (int cb = 0; cb < NCBG; ++cb) {
    const size_t o = (size_t)cb * NTOK + n;
    const float v1 = pv1[o], v2 = pv2[o];
    const int c1 = pc1[o];
    if (v1 > V1) { V2 = fmaxf(V1, v2); V1 = v1; C1 = c1; }
    else V2 = fmaxf(V2, v1);
  }
  final_idx[n] = C1;
  if (V1 - V2 < HMARGIN) {
    const int p = atomicAdd(ucount, 1);
    ulist[p] = n;
  }
}

// ---- kernel 4: exact fp32 rescore, batched: 64 tokens x 256-code slice ----
// grid 512 = 16 token-group slots x 32 slices; thread = (cgrp=tid>>4: 16 codes, tgrp=tid&15: 4 toks)
__global__ __launch_bounds__(256) void rescore_kernel(
    const float* __restrict__ x, const float* __restrict__ w,
    const float* __restrict__ wnf, const float* __restrict__ sumx,
    const int* __restrict__ ucount, const int* __restrict__ ulist,
    float* __restrict__ p2v, int* __restrict__ p2c) {
  const int uc = *ucount;
  if (uc == 0) return;
  const int sl = blockIdx.x & 31, g0 = blockIdx.x >> 5;
  __shared__ float xg[64 * 36];    //  9216 B, row-major [tok][d-chunk], stride 36
  __shared__ float wg[256 * 36];   // 36864 B, row-major [code][d-chunk]
  __shared__ int tokid[64];
  __shared__ float sxs[64];
  __shared__ float rvv[64 * 16];
  __shared__ int rvc[64 * 16];
  const int tid = threadIdx.x;
  const int cgrp = tid >> 4, tgrp = tid & 15;

  for (int g = g0; g * 64 < uc; g += 16) {
    __syncthreads();
    if (tid < 64) {
      const int s = g * 64 + tid;
      const int tk = (s < uc) ? ulist[s] : ulist[0];
      tokid[tid] = tk;
      sxs[tid] = sumx[tk];
    }
    __syncthreads();
    float acc[4][16];
#pragma unroll
    for (int i = 0; i < 4; ++i)
#pragma unroll
      for (int j = 0; j < 16; ++j) acc[i][j] = 0.f;

    for (int dc = 0; dc < 8; ++dc) {
      __syncthreads();
      {  // stage w chunk: thread <-> code row; 32 floats each
        const float4* src = (const float4*)(w + (size_t)(sl * 256 + tid) * DIM + dc * 32);
#pragma unroll
        for (int k = 0; k < 8; ++k) *(float4*)(wg + tid * 36 + k * 4) = src[k];
      }
      {  // stage x chunk: thread -> (tok=tid>>2, q=tid&3), 8 floats
        const int tk = tokid[tid >> 2];
        const float4* src = (const float4*)(x + (size_t)tk * DIM + dc * 32 + (tid & 3) * 8);
        *(float4*)(xg + (tid >> 2) * 36 + (tid & 3) * 8) = src[0];
        *(float4*)(xg + (tid >> 2) * 36 + (tid & 3) * 8 + 4) = src[1];
      }
      __syncthreads();
#pragma unroll
      for (int dg = 0; dg < 8; ++dg) {
        float4 a[4];
#pragma unroll
        for (int i = 0; i < 4; ++i)
          a[i] = *(const float4*)(xg + (tgrp * 4 + i) * 36 + dg * 4);
#pragma unroll
        for (int j = 0; j < 16; ++j) {
          const float4 b = *(const float4*)(wg + (cgrp * 16 + j) * 36 + dg * 4);
#pragma unroll
          for (int i = 0; i < 4; ++i) {
            float t = acc[i][j];
            t = fmaf(a[i].x, b.x, t);
            t = fmaf(a[i].y, b.y, t);
            t = fmaf(a[i].z, b.z, t);
            t = fmaf(a[i].w, b.w, t);
            acc[i][j] = t;
          }
        }
      }
    }
    // dist = (sumx + wn) - 2*dot ; per-thread best over 16 codes (ascending j)
    __syncthreads();
#pragma unroll
    for (int i = 0; i < 4; ++i) {
      const int tokslot = tgrp * 4 + i;
      const float sx = sxs[tokslot];
      float bv = -3.4e38f;
      int bc = 0;
#pragma unroll
      for (int j = 0; j < 16; ++j) {
        const int c = sl * 256 + cgrp * 16 + j;
        const float dist = (sx + wnf[c]) - 2.0f * acc[i][j];
        if (dist > bv) { bv = dist; bc = c; }
      }
      rvv[tokslot * 16 + cgrp] = bv;
      rvc[tokslot * 16 + cgrp] = bc;
    }
    __syncthreads();
    if (tid < 64) {
      const int s = g * 64 + tid;
      if (s < uc) {
        float V = rvv[tid * 16];
        int C = rvc[tid * 16];
#pragma unroll
        for (int k = 1; k < 16; ++k) {
          const float v = rvv[tid * 16 + k];
          const int c = rvc[tid * 16 + k];
          if (v > V || (v == V && c < C)) { V = v; C = c; }
        }
        p2v[((size_t)sl << 14) + s] = V;
        p2c[((size_t)sl << 14) + s] = C;
      }
    }
  }
}

// ---- kernel 5: merge 32 slices per uncertain token ----
__global__ __launch_bounds__(256) void p2merge_kernel(const int* __restrict__ ucount,
    const int* __restrict__ ulist, const float* __restrict__ p2v,
    const int* __restrict__ p2c, int* __restrict__ final_idx) {
  const int s = blockIdx.x * 256 + threadIdx.x;
  if (s >= *ucount) return;
  float V = -3.4e38f;
  int C = 0;
#pragma unroll 8
  for (int sl = 0; sl < 32; ++sl) {
    const float v = p2v[((size_t)sl << 14) + s];
    const int c = p2c[((size_t)sl << 14) + s];
    if (v > V || (v == V && c < C)) { V = v; C = c; }
  }
  final_idx[ulist[s]] = C;
}

// ---- kernel 6: gather output rows ----
__global__ __launch_bounds__(256) void gather_kernel(const float* __restrict__ w,
    const int* __restrict__ final_idx, float* __restrict__ out) {
  const int lane = threadIdx.x & 63;
  const int n = blockIdx.x * 4 + (threadIdx.x >> 6);
  const int bi = final_idx[n];
  ((float4*)(out + (size_t)n * DIM))[lane] = ((const float4*)(w + (size_t)bi * DIM))[lane];
}

extern "C" void kernel_launch(void* const* d_in, const int* in_sizes, int n_in,
                              void* d_out, int out_size, void* d_ws, size_t ws_size,
                              hipStream_t stream) {
  const float* x = (const float*)d_in[0];
  const float* w = (const float*)d_in[1];
  float* out = (float*)d_out;

  char* ws = (char*)d_ws;   // ~17 MB used
  unsigned short* x0n = (unsigned short*)(ws);            // 8388608
  unsigned short* w0 = (unsigned short*)(ws + 8388608);   // 4194304
  float* wn2  = (float*)(ws + 12582912);                  // 32768
  float* wnf  = (float*)(ws + 12615680);                  // 32768
  float* sumx = (float*)(ws + 12648448);                  // 65536
  float* pv1  = (float*)(ws + 12713984);                  // 262144
  int*   pc1  = (int*)  (ws + 12976128);                  // 262144
  float* pv2  = (float*)(ws + 13238272);                  // 262144
  int* final_idx = (int*)(ws + 13500416);                 // 65536
  int* ucount = (int*)(ws + 13565952);                    // 256
  int* ulist  = (int*)(ws + 13566208);                    // 65536
  float* p2v  = (float*)(ws + 13631744);                  // 2097152
  int*   p2c  = (int*)  (ws + 15728896);                  // 2097152

  prep_kernel<<<3072, 256, 0, stream>>>(x, w, x0n, w0, sumx, wn2, wnf, ucount);
  phase1_kernel<<<128 * NCBG, 256, 0, stream>>>(x0n, w0, wn2, pv1, pc1, pv2);
  reduce_kernel<<<NTOK / 256, 256, 0, stream>>>(pv1, pc1, pv2, final_idx, ucount, ulist);
  rescore_kernel<<<16 * 32, 256, 0, stream>>>(x, w, wnf, sumx, ucount, ulist, p2v, p2c);
  p2merge_kernel<<<NTOK / 256, 256, 0, stream>>>(ucount, ulist, p2v, p2c, final_idx);
  gather_kernel<<<NTOK / 4, 256, 0, stream>>>(w, final_idx, out);
}

// Round 5
// 363.237 us; speedup vs baseline: 1.6415x; 1.0754x over previous
//
#include <hip/hip_runtime.h>
#include <cstddef>
#include <cstdint>

#define DIM   256
#define KCODE 8192
#define NTOK  16384
#define NCBG  4          // code groups of 2048 in phase1
#define HMARGIN 0.25f    // phase1 works in half-units (0.5*wn - dot); 0.25 = 0.5 full

typedef __attribute__((ext_vector_type(8))) short short8;
typedef __attribute__((ext_vector_type(8))) unsigned short ushort8;
typedef __attribute__((ext_vector_type(4))) float floatx4;

// RNE float->bf16
__device__ __forceinline__ unsigned short f2bf(float f) {
  uint32_t u = __builtin_bit_cast(uint32_t, f);
  return (unsigned short)((u + 0x7fffu + ((u >> 16) & 1u)) >> 16);
}

// ---- kernel 1: bf16 convert (x NEGATED) + row sumsq; 8 rows/block ----
__global__ __launch_bounds__(256) void prep_kernel(const float* __restrict__ x,
    const float* __restrict__ w, unsigned short* __restrict__ x0n,
    unsigned short* __restrict__ w0, float* __restrict__ sumx,
    float* __restrict__ wn2, float* __restrict__ wnf, int* __restrict__ ucount) {
  if (blockIdx.x == 0 && threadIdx.x == 0) *ucount = 0;
  const int lane = threadIdx.x & 63, wv = threadIdx.x >> 6;
  const int l32 = lane & 31;
  const int row = blockIdx.x * 8 + wv * 2 + (lane >> 5);
  const bool is_x = row < NTOK;
  const float* src = is_x ? (x + (size_t)row * DIM) : (w + (size_t)(row - NTOK) * DIM);
  const float4 f0 = ((const float4*)src)[l32 * 2];
  const float4 f1 = ((const float4*)src)[l32 * 2 + 1];
  ushort8 o;
  if (is_x) {  // store NEGATED x in bf16: MFMA then accumulates wn/2 - dot directly
    o[0] = f2bf(-f0.x); o[1] = f2bf(-f0.y); o[2] = f2bf(-f0.z); o[3] = f2bf(-f0.w);
    o[4] = f2bf(-f1.x); o[5] = f2bf(-f1.y); o[6] = f2bf(-f1.z); o[7] = f2bf(-f1.w);
    *(ushort8*)(x0n + (size_t)row * DIM + l32 * 8) = o;
  } else {
    o[0] = f2bf(f0.x); o[1] = f2bf(f0.y); o[2] = f2bf(f0.z); o[3] = f2bf(f0.w);
    o[4] = f2bf(f1.x); o[5] = f2bf(f1.y); o[6] = f2bf(f1.z); o[7] = f2bf(f1.w);
    *(ushort8*)(w0 + (size_t)(row - NTOK) * DIM + l32 * 8) = o;
  }
  float s = f0.x * f0.x + f0.y * f0.y + f0.z * f0.z + f0.w * f0.w +
            f1.x * f1.x + f1.y * f1.y + f1.z * f1.z + f1.w * f1.w;
#pragma unroll
  for (int off = 1; off < 32; off <<= 1) s += __shfl_xor(s, off);
  if (l32 == 0) {
    if (is_x) sumx[row] = s;
    else { wn2[row - NTOK] = 0.5f * s; wnf[row - NTOK] = s; }
  }
}

// ---- kernel 2: phase1 — A resident in VGPRs, B streamed from L2, one epilogue ----
// block = 128 tokens x 2048 codes; waves: wm=token half(64), wnn=code half(32/sub)
// amdgpu_waves_per_eu(2,2): allocator may use 256 VGPRs -> no scratch spills (R4 bug)
__global__ __launch_bounds__(256) __attribute__((amdgpu_waves_per_eu(2, 2)))
void phase1_kernel(
    const unsigned short* __restrict__ x0n, const unsigned short* __restrict__ w0,
    const float* __restrict__ wn2,
    float* __restrict__ pv1, int* __restrict__ pc1, float* __restrict__ pv2) {
  __shared__ float red[12288];  // 48 KB: rv1[4096] rv2[4096] rc1[4096]
  const int tid = threadIdx.x;
  const int tb = blockIdx.x >> 2;    // 0..127
  const int cbg = blockIdx.x & 3;    // blockIdx%8 fixes XCD -> 1MB w0 slice per XCD L2
  const int lane = tid & 63, wv = tid >> 6;
  const int wm = wv & 1, wnn = wv >> 1;
  const int l15 = lane & 15, quad = lane >> 4;

  // resident A fragments: 4 mt x 8 kc (negated-x bf16) = 128 VGPRs
  short8 af[4][8];
#pragma unroll
  for (int mt = 0; mt < 4; ++mt) {
    const unsigned short* xr =
        x0n + (size_t)(tb * 128 + wm * 64 + mt * 16 + l15) * DIM + quad * 8;
#pragma unroll
    for (int kc = 0; kc < 8; ++kc) af[mt][kc] = *(const short8*)(xr + kc * 32);
  }

  float bv1[16], bv2[16];
  int bc1[16];
#pragma unroll
  for (int i = 0; i < 16; ++i) { bv1[i] = -3.4e38f; bv2[i] = -3.4e38f; bc1[i] = 0; }

  const unsigned short* wp =
      w0 + (size_t)(cbg * 2048 + wnn * 32 + l15) * DIM + quad * 8;
  const float* wnp = wn2 + cbg * 2048 + wnn * 32 + l15;
  int code0 = cbg * 2048 + wnn * 32 + l15;

#pragma unroll 1
  for (int sub = 0; sub < 32; ++sub) {
    const float wn2v0 = wnp[0], wn2v1 = wnp[16];
    floatx4 acc[4][2];
#pragma unroll
    for (int mt = 0; mt < 4; ++mt) {
      acc[mt][0] = (floatx4){wn2v0, wn2v0, wn2v0, wn2v0};
      acc[mt][1] = (floatx4){wn2v1, wn2v1, wn2v1, wn2v1};
    }
#pragma unroll
    for (int kc = 0; kc < 8; ++kc) {
      const short8 b0 = *(const short8*)(wp + kc * 32);
      const short8 b1 = *(const short8*)(wp + 16 * DIM + kc * 32);
#pragma unroll
      for (int mt = 0; mt < 4; ++mt) {
        acc[mt][0] = __builtin_amdgcn_mfma_f32_16x16x32_bf16(af[mt][kc], b0, acc[mt][0], 0, 0, 0);
        acc[mt][1] = __builtin_amdgcn_mfma_f32_16x16x32_bf16(af[mt][kc], b1, acc[mt][1], 0, 0, 0);
      }
    }
    // acc = wn/2 - dot (half-dist, exact fp32 of the bf16 product). 4 VALU/candidate.
#pragma unroll
    for (int mt = 0; mt < 4; ++mt) {
#pragma unroll
      for (int reg = 0; reg < 4; ++reg) {
        const int cell = mt * 4 + reg;
        const float c0 = acc[mt][0][reg], c1 = acc[mt][1][reg];
        const float hi = fmaxf(c0, c1), lo = fminf(c0, c1);
        const int ch = (c1 > c0) ? (code0 + 16) : code0;  // tie -> lower code
        const float t = fminf(bv1[cell], hi);
        bc1[cell] = (hi > bv1[cell]) ? ch : bc1[cell];    // tie -> earlier (lower) code
        bv1[cell] = fmaxf(bv1[cell], hi);
        bv2[cell] = fmaxf(fmaxf(bv2[cell], t), lo);       // v_max3_f32
      }
    }
    wp += (size_t)64 * DIM;
    wnp += 64;
    code0 += 64;
  }

  // single per-block epilogue: cross-column reduce via LDS
  float* rv1 = red;
  float* rv2 = red + 4096;
  int* rc1 = (int*)(red + 8192);
  const int cg = wnn * 16 + l15;
#pragma unroll
  for (int mt = 0; mt < 4; ++mt)
#pragma unroll
    for (int reg = 0; reg < 4; ++reg) {
      const int tok = wm * 64 + mt * 16 + quad * 4 + reg;  // C/D: row=quad*4+reg, col=l15
      rv1[tok * 32 + cg] = bv1[mt * 4 + reg];
      rv2[tok * 32 + cg] = bv2[mt * 4 + reg];
      rc1[tok * 32 + cg] = bc1[mt * 4 + reg];
    }
  __syncthreads();
  if (tid < 128) {
    float V1 = rv1[tid * 32], V2 = rv2[tid * 32];
    int C1 = rc1[tid * 32];
#pragma unroll 4
    for (int j = 1; j < 32; ++j) {
      const float v1 = rv1[tid * 32 + j], v2 = rv2[tid * 32 + j];
      const int c1 = rc1[tid * 32 + j];
      if (v1 > V1) { V2 = fmaxf(V1, v2); V1 = v1; C1 = c1; }
      else V2 = fmaxf(V2, v1);   // exact tie -> gap 0 -> uncertain -> exact rescore
    }
    const size_t o = (size_t)cbg * NTOK + tb * 128 + tid;
    pv1[o] = V1; pc1[o] = C1; pv2[o] = V2;
  }
}

// ---- kernel 3: merge 4 code-group partials; final idx + uncertain list ----
__global__ __launch_bounds__(256) void reduce_kernel(
    const float* __restrict__ pv1, const int* __restrict__ pc1,
    const float* __restrict__ pv2, int* __restrict__ final_idx,
    int* __restrict__ ucount, int* __restrict__ ulist) {
  const int n = blockIdx.x * 256 + threadIdx.x;
  float V1 = -3.4e38f, V2 = -3.4e38f;
  int C1 = 0;
#pragma unroll
  for (int cb = 0; cb < NCBG; ++cb) {
    const size_t o = (size_t)cb * NTOK + n;
    const float v1 = pv1[o], v2 = pv2[o];
    const int c1 = pc1[o];
    if (v1 > V1) { V2 = fmaxf(V1, v2); V1 = v1; C1 = c1; }
    else V2 = fmaxf(V2, v1);
  }
  final_idx[n] = C1;
  if (V1 - V2 < HMARGIN) {
    const int p = atomicAdd(ucount, 1);
    ulist[p] = n;
  }
}

// ---- kernel 4: exact fp32 rescore, batched: 64 tokens x 256-code slice ----
// grid 2048 = 64 token-group slots x 32 slices; thread = (cgrp=tid>>4, tgrp=tid&15)
__global__ __launch_bounds__(256) void rescore_kernel(
    const float* __restrict__ x, const float* __restrict__ w,
    const float* __restrict__ wnf, const float* __restrict__ sumx,
    const int* __restrict__ ucount, const int* __restrict__ ulist,
    float* __restrict__ p2v, int* __restrict__ p2c) {
  const int uc = *ucount;
  if (uc == 0) return;
  const int sl = blockIdx.x & 31, g0 = blockIdx.x >> 5;
  __shared__ float xg[64 * 36];    //  9216 B, row-major [tok][d-chunk], stride 36
  __shared__ float wg[256 * 36];   // 36864 B, row-major [code][d-chunk]
  __shared__ int tokid[64];
  __shared__ float sxs[64];
  __shared__ float rvv[64 * 16];
  __shared__ int rvc[64 * 16];
  const int tid = threadIdx.x;
  const int cgrp = tid >> 4, tgrp = tid & 15;

  for (int g = g0; g * 64 < uc; g += 64) {
    __syncthreads();
    if (tid < 64) {
      const int s = g * 64 + tid;
      const int tk = (s < uc) ? ulist[s] : ulist[0];
      tokid[tid] = tk;
      sxs[tid] = sumx[tk];
    }
    __syncthreads();
    float acc[4][16];
#pragma unroll
    for (int i = 0; i < 4; ++i)
#pragma unroll
      for (int j = 0; j < 16; ++j) acc[i][j] = 0.f;

    for (int dc = 0; dc < 8; ++dc) {
      __syncthreads();
      {  // stage w chunk: thread <-> code row; 32 floats each (128 B line per thread)
        const float4* src = (const float4*)(w + (size_t)(sl * 256 + tid) * DIM + dc * 32);
#pragma unroll
        for (int k = 0; k < 8; ++k) *(float4*)(wg + tid * 36 + k * 4) = src[k];
      }
      {  // stage x chunk: thread -> (tok=tid>>2, q=tid&3), 8 floats
        const int tk = tokid[tid >> 2];
        const float4* src = (const float4*)(x + (size_t)tk * DIM + dc * 32 + (tid & 3) * 8);
        *(float4*)(xg + (tid >> 2) * 36 + (tid & 3) * 8) = src[0];
        *(float4*)(xg + (tid >> 2) * 36 + (tid & 3) * 8 + 4) = src[1];
      }
      __syncthreads();
#pragma unroll
      for (int dg = 0; dg < 8; ++dg) {
        float4 a[4];
#pragma unroll
        for (int i = 0; i < 4; ++i)
          a[i] = *(const float4*)(xg + (tgrp * 4 + i) * 36 + dg * 4);
#pragma unroll
        for (int j = 0; j < 16; ++j) {
          const float4 b = *(const float4*)(wg + (cgrp * 16 + j) * 36 + dg * 4);
#pragma unroll
          for (int i = 0; i < 4; ++i) {
            float t = acc[i][j];
            t = fmaf(a[i].x, b.x, t);
            t = fmaf(a[i].y, b.y, t);
            t = fmaf(a[i].z, b.z, t);
            t = fmaf(a[i].w, b.w, t);
            acc[i][j] = t;
          }
        }
      }
    }
    // dist = (sumx + wn) - 2*dot ; per-thread best over 16 codes (ascending j)
    __syncthreads();
#pragma unroll
    for (int i = 0; i < 4; ++i) {
      const int tokslot = tgrp * 4 + i;
      const float sx = sxs[tokslot];
      float bv = -3.4e38f;
      int bc = 0;
#pragma unroll
      for (int j = 0; j < 16; ++j) {
        const int c = sl * 256 + cgrp * 16 + j;
        const float dist = (sx + wnf[c]) - 2.0f * acc[i][j];
        if (dist > bv) { bv = dist; bc = c; }
      }
      rvv[tokslot * 16 + cgrp] = bv;
      rvc[tokslot * 16 + cgrp] = bc;
    }
    __syncthreads();
    if (tid < 64) {
      const int s = g * 64 + tid;
      if (s < uc) {
        float V = rvv[tid * 16];
        int C = rvc[tid * 16];
#pragma unroll
        for (int k = 1; k < 16; ++k) {
          const float v = rvv[tid * 16 + k];
          const int c = rvc[tid * 16 + k];
          if (v > V || (v == V && c < C)) { V = v; C = c; }
        }
        p2v[((size_t)sl << 14) + s] = V;
        p2c[((size_t)sl << 14) + s] = C;
      }
    }
  }
}

// ---- kernel 5: merge 32 slices per uncertain token ----
__global__ __launch_bounds__(256) void p2merge_kernel(const int* __restrict__ ucount,
    const int* __restrict__ ulist, const float* __restrict__ p2v,
    const int* __restrict__ p2c, int* __restrict__ final_idx) {
  const int s = blockIdx.x * 256 + threadIdx.x;
  if (s >= *ucount) return;
  float V = -3.4e38f;
  int C = 0;
#pragma unroll 8
  for (int sl = 0; sl < 32; ++sl) {
    const float v = p2v[((size_t)sl << 14) + s];
    const int c = p2c[((size_t)sl << 14) + s];
    if (v > V || (v == V && c < C)) { V = v; C = c; }
  }
  final_idx[ulist[s]] = C;
}

// ---- kernel 6: gather output rows ----
__global__ __launch_bounds__(256) void gather_kernel(const float* __restrict__ w,
    const int* __restrict__ final_idx, float* __restrict__ out) {
  const int lane = threadIdx.x & 63;
  const int n = blockIdx.x * 4 + (threadIdx.x >> 6);
  const int bi = final_idx[n];
  ((float4*)(out + (size_t)n * DIM))[lane] = ((const float4*)(w + (size_t)bi * DIM))[lane];
}

extern "C" void kernel_launch(void* const* d_in, const int* in_sizes, int n_in,
                              void* d_out, int out_size, void* d_ws, size_t ws_size,
                              hipStream_t stream) {
  const float* x = (const float*)d_in[0];
  const float* w = (const float*)d_in[1];
  float* out = (float*)d_out;

  char* ws = (char*)d_ws;   // ~17 MB used
  unsigned short* x0n = (unsigned short*)(ws);            // 8388608
  unsigned short* w0 = (unsigned short*)(ws + 8388608);   // 4194304
  float* wn2  = (float*)(ws + 12582912);                  // 32768
  float* wnf  = (float*)(ws + 12615680);                  // 32768
  float* sumx = (float*)(ws + 12648448);                  // 65536
  float* pv1  = (float*)(ws + 12713984);                  // 262144
  int*   pc1  = (int*)  (ws + 12976128);                  // 262144
  float* pv2  = (float*)(ws + 13238272);                  // 262144
  int* final_idx = (int*)(ws + 13500416);                 // 65536
  int* ucount = (int*)(ws + 13565952);                    // 256
  int* ulist  = (int*)(ws + 13566208);                    // 65536
  float* p2v  = (float*)(ws + 13631744);                  // 2097152
  int*   p2c  = (int*)  (ws + 15728896);                  // 2097152

  prep_kernel<<<3072, 256, 0, stream>>>(x, w, x0n, w0, sumx, wn2, wnf, ucount);
  phase1_kernel<<<128 * NCBG, 256, 0, stream>>>(x0n, w0, wn2, pv1, pc1, pv2);
  reduce_kernel<<<NTOK / 256, 256, 0, stream>>>(pv1, pc1, pv2, final_idx, ucount, ulist);
  rescore_kernel<<<64 * 32, 256, 0, stream>>>(x, w, wnf, sumx, ucount, ulist, p2v, p2c);
  p2merge_kernel<<<NTOK / 256, 256, 0, stream>>>(ucount, ulist, p2v, p2c, final_idx);
  gather_kernel<<<NTOK / 4, 256, 0, stream>>>(w, final_idx, out);
}